// Round 9
// baseline (86.173 us; speedup 1.0000x reference)
//
#include <hip/hip_runtime.h>
#include <math.h>

#define EPS_F 1e-8f
#define NS 10
#define NK 11
#define HDIM 256
#define ROWS_PER_BLOCK 4
#define LOG2E_F 1.44269504088896340736f

// Pade [5/4] tanh: tanh x ~= x(1 + y/9 + y^2/945)/(1 + 4y/9 + y^2/63), y=x^2
#define PA1 1.1111111e-1f
#define PA2 1.0582011e-3f
#define PB1 4.4444445e-1f
#define PB2 1.5873016e-2f

__device__ __forceinline__ float softplus_f(float x) {
    // log(1 + e^x) = max(x,0) + log(1 + e^{-|x|})  — stable
    float e = __expf(-fabsf(x));
    return fmaxf(x, 0.0f) + __logf(1.0f + e);
}

// One pair of element-evals, fully hand-scheduled: 26 instructions, no remat,
// no copies. Two independent chains give >=1-instr gaps after each trans op.
// exponent = dlg * uk (dlg has -log2e*dur folded; uk==1.0 for the observed eval)
__device__ __forceinline__ void pair_eval(float uk,
                                          float dlg0, float dlg1,
                                          float dx0,  float dx1,
                                          float cb0,  float cb1,
                                          float ow0,  float ow1,
                                          float pa1,  float pa2,
                                          float pb1,  float pb2,
                                          float& acc)
{
    float t0, t1, c0, c1, y0, y1, n0, n1, d0, d1, w0, w1, p;
    asm volatile(
        "v_mul_f32 %[t0], %[dlg0], %[u]\n\t"
        "v_mul_f32 %[t1], %[dlg1], %[u]\n\t"
        "v_exp_f32 %[t0], %[t0]\n\t"
        "v_exp_f32 %[t1], %[t1]\n\t"
        "v_fma_f32 %[c0], %[dx0], %[t0], %[cb0]\n\t"
        "v_fma_f32 %[c1], %[dx1], %[t1], %[cb1]\n\t"
        "v_mul_f32 %[y0], %[c0], %[c0]\n\t"
        "v_mul_f32 %[y1], %[c1], %[c1]\n\t"
        "v_fma_f32 %[n0], %[y0], %[pa2], %[pa1]\n\t"
        "v_fma_f32 %[n1], %[y1], %[pa2], %[pa1]\n\t"
        "v_fma_f32 %[d0], %[y0], %[pb2], %[pb1]\n\t"
        "v_fma_f32 %[d1], %[y1], %[pb2], %[pb1]\n\t"
        "v_fma_f32 %[n0], %[y0], %[n0], 1.0\n\t"
        "v_fma_f32 %[n1], %[y1], %[n1], 1.0\n\t"
        "v_fma_f32 %[d0], %[y0], %[d0], 1.0\n\t"
        "v_fma_f32 %[d1], %[y1], %[d1], 1.0\n\t"
        "v_mul_f32 %[w0], %[ow0], %[c0]\n\t"
        "v_mul_f32 %[w1], %[ow1], %[c1]\n\t"
        "v_mul_f32 %[p], %[d0], %[d1]\n\t"
        "v_rcp_f32 %[p], %[p]\n\t"
        "v_mul_f32 %[n0], %[n0], %[w0]\n\t"
        "v_mul_f32 %[n1], %[n1], %[w1]\n\t"
        "v_mul_f32 %[d1], %[d1], %[p]\n\t"   // 1/d0 (old d1 * p)
        "v_mul_f32 %[d0], %[d0], %[p]\n\t"   // 1/d1 (old d0 * p)
        "v_fmac_f32 %[acc], %[n0], %[d1]\n\t"
        "v_fmac_f32 %[acc], %[n1], %[d0]\n\t"
        : [t0]"=&v"(t0), [t1]"=&v"(t1), [c0]"=&v"(c0), [c1]"=&v"(c1),
          [y0]"=&v"(y0), [y1]"=&v"(y1), [n0]"=&v"(n0), [n1]"=&v"(n1),
          [d0]"=&v"(d0), [d1]"=&v"(d1), [w0]"=&v"(w0), [w1]"=&v"(w1),
          [p]"=&v"(p), [acc]"+v"(acc)
        : [u]"v"(uk), [dlg0]"v"(dlg0), [dlg1]"v"(dlg1),
          [dx0]"v"(dx0), [dx1]"v"(dx1), [cb0]"v"(cb0), [cb1]"v"(cb1),
          [ow0]"v"(ow0), [ow1]"v"(ow1),
          [pa1]"v"(pa1), [pa2]"v"(pa2), [pb1]"v"(pb1), [pb2]"v"(pb2));
}

__global__ __launch_bounds__(256) void intensity_loss_kernel(
    const float* __restrict__ duration,   // [B]
    const float* __restrict__ cx,         // [B,H]
    const float* __restrict__ cbarx,      // [B,H]
    const float* __restrict__ deltx,      // [B,H]
    const float* __restrict__ ox,         // [B,H]
    const float* __restrict__ W,          // [H]
    const float* __restrict__ bptr,       // [1]
    const float* __restrict__ u,          // [NS,B]
    float* __restrict__ out,              // [B]
    int B)
{
    const int wave = threadIdx.x >> 6;
    const int lane = threadIdx.x & 63;
    const int row  = blockIdx.x * ROWS_PER_BLOCK + wave;
    if (row >= B) return;

    const size_t base = (size_t)row * HDIM + (size_t)(lane << 2);

    const float4 vcx = *reinterpret_cast<const float4*>(cx    + base);
    const float4 vcb = *reinterpret_cast<const float4*>(cbarx + base);
    const float4 vdl = *reinterpret_cast<const float4*>(deltx + base);
    const float4 vox = *reinterpret_cast<const float4*>(ox    + base);
    const float4 vw  = *reinterpret_cast<const float4*>(W + (lane << 2));

    const float dur = duration[row];

    // u samples (vector loads — R7-proven); slot 0 = observed eval (u == 1)
    float us[NK];
    us[0] = 1.0f;
#pragma unroll
    for (int s = 0; s < NS; ++s)
        us[s + 1] = u[(size_t)s * (size_t)B + (size_t)row];

    // per-row invariants; fold (-log2e * dur) into delta: exponent = dlgd * u_k
    const float nld = -LOG2E_F * dur;
    float cb[4]   = {vcb.x, vcb.y, vcb.z, vcb.w};
    float dx[4]   = {vcx.x - vcb.x, vcx.y - vcb.y, vcx.z - vcb.z, vcx.w - vcb.w};
    float dlgd[4] = {vdl.x * nld, vdl.y * nld, vdl.z * nld, vdl.w * nld};
    float ow[4]   = {vox.x * vw.x, vox.y * vw.y, vox.z * vw.z, vox.w * vw.w};

    // Pade coefficients as VGPR-resident values for the asm blocks
    float pa1 = PA1, pa2 = PA2, pb1 = PB1, pb2 = PB2;

    float acc[NK];
#pragma unroll
    for (int k = 0; k < NK; ++k) {
        float a = 0.0f;
        pair_eval(us[k], dlgd[0], dlgd[1], dx[0], dx[1], cb[0], cb[1],
                  ow[0], ow[1], pa1, pa2, pb1, pb2, a);
        pair_eval(us[k], dlgd[2], dlgd[3], dx[2], dx[3], cb[2], cb[3],
                  ow[2], ow[3], pa1, pa2, pb1, pb2, a);
        acc[k] = a;
    }

    // batched butterfly: issue all 11 shuffles per step so latencies overlap
#pragma unroll
    for (int off = 32; off > 0; off >>= 1) {
        float tmp[NK];
#pragma unroll
        for (int k = 0; k < NK; ++k) tmp[k] = __shfl_xor(acc[k], off, 64);
#pragma unroll
        for (int k = 0; k < NK; ++k) acc[k] += tmp[k];
    }

    // wave-parallel epilogue: lane k owns acc[k] (k=0..10)
    const float bb = bptr[0];
    float z = acc[0];
#pragma unroll
    for (int k = 1; k < NK; ++k) z = (lane == k) ? acc[k] : z;

    float sp   = softplus_f(z + bb);
    float nllv = -__logf(sp + EPS_F);
    const float scale = dur * (1.0f / (float)NS);

    float contrib = (lane == 0) ? nllv
                  : ((lane <= NS) ? sp * scale : 0.0f);

    // lanes 0..10 live within one 16-lane row -> 4 steps suffice
#pragma unroll
    for (int off = 8; off > 0; off >>= 1)
        contrib += __shfl_xor(contrib, off, 64);

    if (lane == 0) out[row] = contrib;
}

extern "C" void kernel_launch(void* const* d_in, const int* in_sizes, int n_in,
                              void* d_out, int out_size, void* d_ws, size_t ws_size,
                              hipStream_t stream) {
    const float* duration = (const float*)d_in[0];
    const float* cx       = (const float*)d_in[1];
    const float* cbarx    = (const float*)d_in[2];
    const float* deltx    = (const float*)d_in[3];
    const float* ox       = (const float*)d_in[4];
    const float* W        = (const float*)d_in[5];
    const float* b        = (const float*)d_in[6];
    const float* u        = (const float*)d_in[7];
    float* out            = (float*)d_out;

    const int B = in_sizes[0];           // 65536
    const int grid = (B + ROWS_PER_BLOCK - 1) / ROWS_PER_BLOCK;

    intensity_loss_kernel<<<grid, 256, 0, stream>>>(
        duration, cx, cbarx, deltx, ox, W, b, u, out, B);
}

// Round 10
// 79.035 us; speedup vs baseline: 1.0903x; 1.0903x over previous
//
#include <hip/hip_runtime.h>
#include <math.h>

#define EPS_F 1e-8f
#define NS 10
#define NK 11
#define HDIM 256
#define ROWS_PER_BLOCK 4
#define LOG2E_F 1.44269504088896340736f

// Pade [5/4] tanh: tanh x ~= x(1 + y/9 + y^2/945)/(1 + 4y/9 + y^2/63), y=x^2
#define PA1 1.1111111e-1f
#define PA2 1.0582011e-3f
#define PB1 4.4444445e-1f
#define PB2 1.5873016e-2f

__device__ __forceinline__ float softplus_f(float x) {
    // log(1 + e^x) = max(x,0) + log(1 + e^{-|x|})  — stable
    float e = __expf(-fabsf(x));
    return fmaxf(x, 0.0f) + __logf(1.0f + e);
}

// plain xor-reduce: result valid in all lanes
__device__ __forceinline__ float xred(float a, int off) {
    return a + __shfl_xor(a, off, 64);
}
// merge-reduce: reduce a and b over the off-pair; lanes with (lane&off)==0
// carry a's sum, lanes with (lane&off)!=0 carry b's sum.
__device__ __forceinline__ float xmerge(float a, float b, int off, int lane) {
    float ra = a + __shfl_xor(a, off, 64);
    float rb = b + __shfl_xor(b, off, 64);
    return (lane & off) ? rb : ra;
}

__global__ __launch_bounds__(256) void intensity_loss_kernel(
    const float* __restrict__ duration,   // [B]
    const float* __restrict__ cx,         // [B,H]
    const float* __restrict__ cbarx,      // [B,H]
    const float* __restrict__ deltx,      // [B,H]
    const float* __restrict__ ox,         // [B,H]
    const float* __restrict__ W,          // [H]
    const float* __restrict__ bptr,       // [1]
    const float* __restrict__ u,          // [NS,B]
    float* __restrict__ out,              // [B]
    int B)
{
    const int wave = threadIdx.x >> 6;
    const int lane = threadIdx.x & 63;
    const int row  = blockIdx.x * ROWS_PER_BLOCK + wave;
    if (row >= B) return;

    const size_t base = (size_t)row * HDIM + (size_t)(lane << 2);

    const float4 vcx = *reinterpret_cast<const float4*>(cx    + base);
    const float4 vcb = *reinterpret_cast<const float4*>(cbarx + base);
    const float4 vdl = *reinterpret_cast<const float4*>(deltx + base);
    const float4 vox = *reinterpret_cast<const float4*>(ox    + base);
    const float4 vw  = *reinterpret_cast<const float4*>(W + (lane << 2));

    const float dur = duration[row];

    // u samples (vector loads — R7-proven); slot 0 = observed eval (u == 1)
    float us[NK];
    us[0] = 1.0f;
#pragma unroll
    for (int s = 0; s < NS; ++s)
        us[s + 1] = u[(size_t)s * (size_t)B + (size_t)row];

    // per-row invariants; fold (-log2e*dur) into delta: exponent = dlgd*u_k;
    // fold ow into the Pade numerator coefficients (saves 1 mul/elem)
    const float nld = -LOG2E_F * dur;
    float cb[4]   = {vcb.x, vcb.y, vcb.z, vcb.w};
    float dx[4]   = {vcx.x - vcb.x, vcx.y - vcb.y, vcx.z - vcb.z, vcx.w - vcb.w};
    float dlgd[4] = {vdl.x * nld, vdl.y * nld, vdl.z * nld, vdl.w * nld};
    float ow[4]   = {vox.x * vw.x, vox.y * vw.y, vox.z * vw.z, vox.w * vw.w};
    float owa1[4], owa2[4];
#pragma unroll
    for (int j = 0; j < 4; ++j) { owa1[j] = ow[j] * PA1; owa2[j] = ow[j] * PA2; }

    float acc[NK];
#pragma unroll
    for (int k = 0; k < NK; ++k) {
        // exponents (k=0 is the observed eval: u==1, skip the mul)
        float e0 = __builtin_amdgcn_exp2f((k == 0) ? dlgd[0] : dlgd[0] * us[k]);
        float e1 = __builtin_amdgcn_exp2f((k == 0) ? dlgd[1] : dlgd[1] * us[k]);
        float e2 = __builtin_amdgcn_exp2f((k == 0) ? dlgd[2] : dlgd[2] * us[k]);
        float e3 = __builtin_amdgcn_exp2f((k == 0) ? dlgd[3] : dlgd[3] * us[k]);
        float c0 = fmaf(dx[0], e0, cb[0]);
        float c1 = fmaf(dx[1], e1, cb[1]);
        float c2 = fmaf(dx[2], e2, cb[2]);
        float c3 = fmaf(dx[3], e3, cb[3]);
        float y0 = c0 * c0, y1 = c1 * c1, y2 = c2 * c2, y3 = c3 * c3;
        // denominators (unclamped Pade[5/4]; |c|<=~5.8 -> den in [1,35])
        float d0 = fmaf(y0, fmaf(y0, PB2, PB1), 1.0f);
        float d1 = fmaf(y1, fmaf(y1, PB2, PB1), 1.0f);
        float d2 = fmaf(y2, fmaf(y2, PB2, PB1), 1.0f);
        float d3 = fmaf(y3, fmaf(y3, PB2, PB1), 1.0f);
        // ow-folded numerators: ow*c*P(y)
        float n0 = c0 * fmaf(y0, fmaf(y0, owa2[0], owa1[0]), ow[0]);
        float n1 = c1 * fmaf(y1, fmaf(y1, owa2[1], owa1[1]), ow[1]);
        float n2 = c2 * fmaf(y2, fmaf(y2, owa2[2], owa1[2]), ow[2]);
        float n3 = c3 * fmaf(y3, fmaf(y3, owa2[3], owa1[3]), ow[3]);
        // ONE rcp for all four denominators (prefix/suffix products)
        float p01 = d0 * d1, p23 = d2 * d3;
        float R   = __builtin_amdgcn_rcpf(p01 * p23);   // P <= ~1.4e6, safe
        float r01 = R * p23, r23 = R * p01;             // 1/(d0*d1), 1/(d2*d3)
        float a;
        a = n0 * (r01 * d1);                            // n0/d0
        a = fmaf(n1, r01 * d0, a);                      // n1/d1
        a = fmaf(n2, r23 * d3, a);                      // n2/d2
        a = fmaf(n3, r23 * d2, a);                      // n3/d3
        acc[k] = a;
    }

    // merged multi-value butterfly along k's binary digits: each step halves
    // the live registers; final register holds k's wave-sum AT lane k.
    // bit0 (off=1)
    float m01 = xmerge(acc[0], acc[1], 1, lane);
    float m23 = xmerge(acc[2], acc[3], 1, lane);
    float m45 = xmerge(acc[4], acc[5], 1, lane);
    float m67 = xmerge(acc[6], acc[7], 1, lane);
    float m89 = xmerge(acc[8], acc[9], 1, lane);
    float mA  = xred(acc[10], 1);
    // bit1 (off=2)
    float q0 = xmerge(m01, m23, 2, lane);
    float q1 = xmerge(m45, m67, 2, lane);
    float q2 = xmerge(m89, mA, 2, lane);   // k=8,9 bit1=0; k=10 bit1=1
    // bit2 (off=4)
    float p0 = xmerge(q0, q1, 4, lane);    // k0-3 vs k4-7
    float p1 = xred(q2, 4);                // k8-10 all bit2=0
    // bit3 (off=8)
    float f = xmerge(p0, p1, 8, lane);     // k0-7 vs k8-10
    // bits 4,5: plain
    f = xred(f, 16);
    f = xred(f, 32);
    // now lane l (l=0..10) holds sum over all 64 lanes of acc[l]

    const float bb = bptr[0];
    float sp   = softplus_f(f + bb);
    float nllv = -__logf(sp + EPS_F);
    const float scale = dur * (1.0f / (float)NS);

    float contrib = (lane == 0) ? nllv
                  : ((lane <= NS) ? sp * scale : 0.0f);

    // lanes 0..10 live within one 16-lane row -> 4 steps suffice
#pragma unroll
    for (int off = 8; off > 0; off >>= 1)
        contrib += __shfl_xor(contrib, off, 64);

    if (lane == 0) out[row] = contrib;
}

extern "C" void kernel_launch(void* const* d_in, const int* in_sizes, int n_in,
                              void* d_out, int out_size, void* d_ws, size_t ws_size,
                              hipStream_t stream) {
    const float* duration = (const float*)d_in[0];
    const float* cx       = (const float*)d_in[1];
    const float* cbarx    = (const float*)d_in[2];
    const float* deltx    = (const float*)d_in[3];
    const float* ox       = (const float*)d_in[4];
    const float* W        = (const float*)d_in[5];
    const float* b        = (const float*)d_in[6];
    const float* u        = (const float*)d_in[7];
    float* out            = (float*)d_out;

    const int B = in_sizes[0];           // 65536
    const int grid = (B + ROWS_PER_BLOCK - 1) / ROWS_PER_BLOCK;

    intensity_loss_kernel<<<grid, 256, 0, stream>>>(
        duration, cx, cbarx, deltx, ox, W, b, u, out, B);
}

// Round 11
// 76.682 us; speedup vs baseline: 1.1238x; 1.0307x over previous
//
#include <hip/hip_runtime.h>
#include <math.h>

#define EPS_F 1e-8f
#define NS 10
#define NK 11
#define HDIM 256
#define ROWS_PER_BLOCK 4
#define LOG2E_F 1.44269504088896340736f

// Pade [5/4] tanh: tanh x ~= x(1 + y/9 + y^2/945)/(1 + 4y/9 + y^2/63), y=x^2
#define PA1 1.1111111e-1f
#define PA2 1.0582011e-3f
#define PB1 4.4444445e-1f
#define PB2 1.5873016e-2f

// quad_perm DPP controls: exact xor permutations within each 4-lane quad
#define QP_XOR1 0xB1   // perm [1,0,3,2]
#define QP_XOR2 0x4E   // perm [2,3,0,1]

// x + x[lane^k] for k=1,2 via quad_perm DPP (pure VALU, no DS pipe)
template <int CTRL>
__device__ __forceinline__ float qperm_add(float x) {
    int t = __builtin_amdgcn_update_dpp(0, __float_as_int(x), CTRL, 0xf, 0xf, true);
    return x + __int_as_float(t);
}
// DPP merge: lanes with (lane&off)==0 keep a's pair-sum, others b's
template <int CTRL>
__device__ __forceinline__ float xmergeq(float a, float b, int off, int lane) {
    float ra = qperm_add<CTRL>(a);
    float rb = qperm_add<CTRL>(b);
    return (lane & off) ? rb : ra;
}
// DS-based fallbacks for xor4/8/16/32 (no DPP equivalent)
__device__ __forceinline__ float xred(float a, int off) {
    return a + __shfl_xor(a, off, 64);
}
__device__ __forceinline__ float xmerge(float a, float b, int off, int lane) {
    float ra = a + __shfl_xor(a, off, 64);
    float rb = b + __shfl_xor(b, off, 64);
    return (lane & off) ? rb : ra;
}

__device__ __forceinline__ float softplus_f(float x) {
    // log(1 + e^x) = max(x,0) + log(1 + e^{-|x|})  — stable
    float e = __expf(-fabsf(x));
    return fmaxf(x, 0.0f) + __logf(1.0f + e);
}

__global__ __launch_bounds__(256) void intensity_loss_kernel(
    const float* __restrict__ duration,   // [B]
    const float* __restrict__ cx,         // [B,H]
    const float* __restrict__ cbarx,      // [B,H]
    const float* __restrict__ deltx,      // [B,H]
    const float* __restrict__ ox,         // [B,H]
    const float* __restrict__ W,          // [H]
    const float* __restrict__ bptr,       // [1]
    const float* __restrict__ u,          // [NS,B]
    float* __restrict__ out,              // [B]
    int B)
{
    const int wave = threadIdx.x >> 6;
    const int lane = threadIdx.x & 63;
    const int row  = blockIdx.x * ROWS_PER_BLOCK + wave;
    if (row >= B) return;

    const size_t base = (size_t)row * HDIM + (size_t)(lane << 2);

    const float4 vcx = *reinterpret_cast<const float4*>(cx    + base);
    const float4 vcb = *reinterpret_cast<const float4*>(cbarx + base);
    const float4 vdl = *reinterpret_cast<const float4*>(deltx + base);
    const float4 vox = *reinterpret_cast<const float4*>(ox    + base);
    const float4 vw  = *reinterpret_cast<const float4*>(W + (lane << 2));

    const float dur = duration[row];

    // u samples (vector loads — R7-proven); slot 0 = observed eval (u == 1)
    float us[NK];
    us[0] = 1.0f;
#pragma unroll
    for (int s = 0; s < NS; ++s)
        us[s + 1] = u[(size_t)s * (size_t)B + (size_t)row];

    // per-row invariants; fold (-log2e*dur) into delta: exponent = dlgd*u_k;
    // fold ow into the Pade numerator coefficients
    const float nld = -LOG2E_F * dur;
    float cb[4]   = {vcb.x, vcb.y, vcb.z, vcb.w};
    float dx[4]   = {vcx.x - vcb.x, vcx.y - vcb.y, vcx.z - vcb.z, vcx.w - vcb.w};
    float dlgd[4] = {vdl.x * nld, vdl.y * nld, vdl.z * nld, vdl.w * nld};
    float ow[4]   = {vox.x * vw.x, vox.y * vw.y, vox.z * vw.z, vox.w * vw.w};
    float owa1[4], owa2[4];
#pragma unroll
    for (int j = 0; j < 4; ++j) { owa1[j] = ow[j] * PA1; owa2[j] = ow[j] * PA2; }

    // Evaluate one time-sample: returns N (numerator) and P (denominator) with
    // sum_j n_j/d_j = N/P.  isObs=true means u==1 (skip the exponent muls).
    auto eval_np = [&](float uk, bool isObs, float& N, float& P) {
        float e0 = __builtin_amdgcn_exp2f(isObs ? dlgd[0] : dlgd[0] * uk);
        float e1 = __builtin_amdgcn_exp2f(isObs ? dlgd[1] : dlgd[1] * uk);
        float e2 = __builtin_amdgcn_exp2f(isObs ? dlgd[2] : dlgd[2] * uk);
        float e3 = __builtin_amdgcn_exp2f(isObs ? dlgd[3] : dlgd[3] * uk);
        float c0 = fmaf(dx[0], e0, cb[0]);
        float c1 = fmaf(dx[1], e1, cb[1]);
        float c2 = fmaf(dx[2], e2, cb[2]);
        float c3 = fmaf(dx[3], e3, cb[3]);
        float y0 = c0 * c0, y1 = c1 * c1, y2 = c2 * c2, y3 = c3 * c3;
        // denominators (unclamped Pade[5/4]; |c|<=~5.8 -> d in [1,35])
        float d0 = fmaf(y0, fmaf(y0, PB2, PB1), 1.0f);
        float d1 = fmaf(y1, fmaf(y1, PB2, PB1), 1.0f);
        float d2 = fmaf(y2, fmaf(y2, PB2, PB1), 1.0f);
        float d3 = fmaf(y3, fmaf(y3, PB2, PB1), 1.0f);
        // ow-folded numerators: n = ow*c*Pnum(y)
        float n0 = c0 * fmaf(y0, fmaf(y0, owa2[0], owa1[0]), ow[0]);
        float n1 = c1 * fmaf(y1, fmaf(y1, owa2[1], owa1[1]), ow[1]);
        float n2 = c2 * fmaf(y2, fmaf(y2, owa2[2], owa1[2]), ow[2]);
        float n3 = c3 * fmaf(y3, fmaf(y3, owa2[3], owa1[3]), ow[3]);
        // single-fraction combine: sum n_i/d_i = N/P
        float p01 = d0 * d1, p23 = d2 * d3;
        float N01 = fmaf(n1, d0, n0 * d1);
        float N23 = fmaf(n3, d2, n2 * d3);
        N = fmaf(N23, p01, N01 * p23);     // |N| <= ~2e6, safe
        P = p01 * p23;                     // <= ~1.5e6, safe
    };

    float acc[NK];
    // k = 0 (observed eval): standalone rcp
    {
        float N0, P0;
        eval_np(1.0f, true, N0, P0);
        acc[0] = N0 * __builtin_amdgcn_rcpf(P0);
    }
    // k = 1..10 in pairs sharing ONE rcp: 1/Pa = R*Pb, 1/Pb = R*Pa
#pragma unroll
    for (int i = 0; i < 5; ++i) {
        const int ka = 2 * i + 1, kb = 2 * i + 2;
        float Na, Pa, Nb, Pb;
        eval_np(us[ka], false, Na, Pa);
        eval_np(us[kb], false, Nb, Pb);
        float R = __builtin_amdgcn_rcpf(Pa * Pb);   // <= ~2.3e12, safe
        acc[ka] = Na * (R * Pb);
        acc[kb] = Nb * (R * Pa);
    }

    // merged multi-value butterfly; xor1/xor2 steps via quad_perm DPP (VALU),
    // xor4/8/16/32 via DS shuffles. Final: lane l holds wave-sum of acc[l].
    float m01 = xmergeq<QP_XOR1>(acc[0], acc[1], 1, lane);
    float m23 = xmergeq<QP_XOR1>(acc[2], acc[3], 1, lane);
    float m45 = xmergeq<QP_XOR1>(acc[4], acc[5], 1, lane);
    float m67 = xmergeq<QP_XOR1>(acc[6], acc[7], 1, lane);
    float m89 = xmergeq<QP_XOR1>(acc[8], acc[9], 1, lane);
    float mA  = qperm_add<QP_XOR1>(acc[10]);
    float q0 = xmergeq<QP_XOR2>(m01, m23, 2, lane);
    float q1 = xmergeq<QP_XOR2>(m45, m67, 2, lane);
    float q2 = xmergeq<QP_XOR2>(m89, mA, 2, lane);
    float p0 = xmerge(q0, q1, 4, lane);
    float p1 = xred(q2, 4);
    float f  = xmerge(p0, p1, 8, lane);
    f = xred(f, 16);
    f = xred(f, 32);

    const float bb = bptr[0];
    float sp   = softplus_f(f + bb);
    float nllv = -__logf(sp + EPS_F);
    const float scale = dur * (1.0f / (float)NS);

    float contrib = (lane == 0) ? nllv
                  : ((lane <= NS) ? sp * scale : 0.0f);

    // lanes 0..10: reduce within 16 — xor8,4 via DS; xor2,1 via DPP
    contrib = xred(contrib, 8);
    contrib = xred(contrib, 4);
    contrib = qperm_add<QP_XOR2>(contrib);
    contrib = qperm_add<QP_XOR1>(contrib);

    if (lane == 0) out[row] = contrib;
}

extern "C" void kernel_launch(void* const* d_in, const int* in_sizes, int n_in,
                              void* d_out, int out_size, void* d_ws, size_t ws_size,
                              hipStream_t stream) {
    const float* duration = (const float*)d_in[0];
    const float* cx       = (const float*)d_in[1];
    const float* cbarx    = (const float*)d_in[2];
    const float* deltx    = (const float*)d_in[3];
    const float* ox       = (const float*)d_in[4];
    const float* W        = (const float*)d_in[5];
    const float* b        = (const float*)d_in[6];
    const float* u        = (const float*)d_in[7];
    float* out            = (float*)d_out;

    const int B = in_sizes[0];           // 65536
    const int grid = (B + ROWS_PER_BLOCK - 1) / ROWS_PER_BLOCK;

    intensity_loss_kernel<<<grid, 256, 0, stream>>>(
        duration, cx, cbarx, deltx, ox, W, b, u, out, B);
}